// Round 4
// baseline (2622.067 us; speedup 1.0000x reference)
//
#include <hip/hip_runtime.h>
#include <hip/hip_bf16.h>

using bf16x8 = __attribute__((ext_vector_type(8))) short;
using f32x4  = __attribute__((ext_vector_type(4))) float;
using u16x4  = __attribute__((ext_vector_type(4))) unsigned short;

constexpr int Ht = 60, Wt = 108, C = 512;
constexpr int GWt = 14, NWIN = 112, NTOK = Ht * Wt, BT = 16;
constexpr float SCALE = 0.08838834764831845f;   // 1/sqrt(128)

// LDS (static 56 KB -> 2 blocks/CU). All tiles XOR-swizzled: byte ^= (row&7)<<4
constexpr int O_Q  = 0;       // [64][128] bf16: Q, then attn_h
constexpr int O_K  = 16384;   // [64][128] bf16: K
constexpr int O_VT = 32768;   // [128][64] bf16: V transposed
constexpr int O_P  = 49152;   // [64][64]  bf16: P
constexpr int LDS_BYTES = 57344;

__device__ __forceinline__ unsigned short f2b(float f) {   // f32 -> bf16 RNE
  union { float f; unsigned u; } v; v.f = f;
  unsigned r = v.u + 0x7fffu + ((v.u >> 16) & 1u);
  return (unsigned short)(r >> 16);
}

__device__ __forceinline__ bf16x8 cvt8(float4 a, float4 b) {  // 8 f32 -> bf16x8 RNE
  union { bf16x8 v; __hip_bfloat162 h[4]; } u;
  u.h[0] = __float22bfloat162_rn(make_float2(a.x, a.y));
  u.h[1] = __float22bfloat162_rn(make_float2(a.z, a.w));
  u.h[2] = __float22bfloat162_rn(make_float2(b.x, b.y));
  u.h[3] = __float22bfloat162_rn(make_float2(b.z, b.w));
  return u.v;
}

__global__ void cvt_weights(const float* __restrict__ a, const float* __restrict__ b,
                            const float* __restrict__ c, const float* __restrict__ d,
                            unsigned short* __restrict__ dst) {
  int i = blockIdx.x * blockDim.x + threadIdx.x;   // 262144 threads, 4 f32 each
  int m  = i >> 16;
  int o4 = i & 65535;
  const float* src = (m == 0) ? a : (m == 1) ? b : (m == 2) ? c : d;
  float4 v = *(const float4*)(src + (size_t)o4 * 4);
  u16x4 o;
  o[0] = f2b(v.x); o[1] = f2b(v.y); o[2] = f2b(v.z); o[3] = f2b(v.w);
  *(u16x4*)(dst + (size_t)m * 262144 + (size_t)o4 * 4) = o;
}

extern "C" __global__ __launch_bounds__(256, 2)
void swmhsa_main(const float* __restrict__ x,
                 const unsigned short* __restrict__ wqkvo,   // [4][512][512] bf16
                 const float* __restrict__ bq, const float* __restrict__ bk,
                 const float* __restrict__ bv, const float* __restrict__ bo,
                 float* __restrict__ out)
{
  __shared__ char smem[LDS_BYTES];
  const int tid   = threadIdx.x;
  const int wvid  = tid >> 6;          // wave 0..3
  const int lane  = tid & 63;
  const int l15   = lane & 15;
  const int kl    = (lane >> 4) << 3;  // per-lane k offset in fragments
  const int rbase = (lane >> 4) << 2;  // acc row base

  char* qb = smem + O_Q;
  char* kb = smem + O_K;
  char* vt = smem + O_VT;
  char* pb = smem + O_P;

  const int blk = blockIdx.x;
  const int b   = blk / NWIN;
  const int w   = blk - b * NWIN;
  const int wy  = w / GWt, wx = w - wy * GWt;

  // per-lane x row pointers for A-fragments (token rows mt*16 + l15); null = padded
  const float* rowp[4];
  #pragma unroll
  for (int mt = 0; mt < 4; ++mt) {
    int r  = mt * 16 + l15;
    int gy = wy * 8 + (r >> 3), gx = wx * 8 + (r & 7);
    rowp[mt] = (gy < Ht && gx < Wt) ? x + ((size_t)b * NTOK + gy * Wt + gx) * C
                                    : (const float*)nullptr;
  }

  auto ldA = [&](int ka, bf16x8 (&afr)[4]) {
    #pragma unroll
    for (int mt = 0; mt < 4; ++mt) {
      if (rowp[mt]) {
        float4 a = *(const float4*)(rowp[mt] + ka);
        float4 c = *(const float4*)(rowp[mt] + ka + 4);
        afr[mt] = cvt8(a, c);
      } else {
        afr[mt] = (bf16x8){0,0,0,0,0,0,0,0};
      }
    }
  };

  // GEMM: [64 x 32cols-per-wave] = x_win(64x512) @ W_h^T ; A from global f32, B bf16
  auto gemm_g = [&](const unsigned short* wm, int h, f32x4 (&acc)[4][2]) {
    #pragma unroll
    for (int mt = 0; mt < 4; ++mt)
      #pragma unroll
      for (int nt = 0; nt < 2; ++nt) acc[mt][nt] = (f32x4){0.f, 0.f, 0.f, 0.f};
    #pragma unroll 2
    for (int kk = 0; kk < 512; kk += 32) {
      int ka = kk + kl;
      bf16x8 afr[4];
      ldA(ka, afr);
      bf16x8 bfr[2];
      #pragma unroll
      for (int nt = 0; nt < 2; ++nt) {
        int jg = h * 128 + wvid * 32 + nt * 16 + l15;
        bfr[nt] = *(const bf16x8*)(wm + (size_t)jg * 512 + ka);
      }
      #pragma unroll
      for (int mt = 0; mt < 4; ++mt)
        #pragma unroll
        for (int nt = 0; nt < 2; ++nt)
          acc[mt][nt] = __builtin_amdgcn_mfma_f32_16x16x32_bf16(afr[mt], bfr[nt], acc[mt][nt], 0, 0, 0);
    }
  };

  // store acc (row=token, col=feature) row-major [64][128] bf16 + bias, swizzled
  auto store_rm = [&](f32x4 (&acc)[4][2], char* base, const float* bias, int h) {
    #pragma unroll
    for (int nt = 0; nt < 2; ++nt) {
      int col = wvid * 32 + nt * 16 + l15;
      float bi = bias[h * 128 + col];
      #pragma unroll
      for (int mt = 0; mt < 4; ++mt)
        #pragma unroll
        for (int rg = 0; rg < 4; ++rg) {
          int row = mt * 16 + rbase + rg;
          int off = (row << 8) + (col << 1);
          off ^= (row & 7) << 4;
          *(unsigned short*)(base + off) = f2b(acc[mt][nt][rg] + bi);
        }
    }
  };

  f32x4 oacc[4][8];                    // persistent: 128 output cols per wave
  #pragma unroll
  for (int mt = 0; mt < 4; ++mt)
    #pragma unroll
    for (int nt = 0; nt < 8; ++nt) oacc[mt][nt] = (f32x4){0.f, 0.f, 0.f, 0.f};

  const unsigned short* wo = wqkvo + 3 * 262144;

  for (int h = 0; h < 4; ++h) {
    // ---- Phase 1: K, Q projections -> LDS ----
    {
      f32x4 acc[4][2];
      gemm_g(wqkvo + 1 * 262144, h, acc);      // K
      store_rm(acc, kb, bk, h);
      gemm_g(wqkvo + 0 * 262144, h, acc);      // Q
      store_rm(acc, qb, bq, h);
    }
    __syncthreads();
    // ---- Phase 2: QK^T + softmax -> P ; V projection -> Vt ----
    {
      f32x4 sacc[4];
      #pragma unroll
      for (int nt = 0; nt < 4; ++nt) sacc[nt] = (f32x4){0.f, 0.f, 0.f, 0.f};
      #pragma unroll
      for (int kk = 0; kk < 128; kk += 32) {
        int ka = kk + kl;
        int row = wvid * 16 + l15;
        int off = (row << 8) + (ka << 1); off ^= (row & 7) << 4;
        bf16x8 afr = *(const bf16x8*)(qb + off);
        #pragma unroll
        for (int nt = 0; nt < 4; ++nt) {
          int jr = nt * 16 + l15;
          int o2 = (jr << 8) + (ka << 1); o2 ^= (jr & 7) << 4;
          bf16x8 bfr = *(const bf16x8*)(kb + o2);
          sacc[nt] = __builtin_amdgcn_mfma_f32_16x16x32_bf16(afr, bfr, sacc[nt], 0, 0, 0);
        }
      }
      // softmax: row wvid*16 + rbase + rg lives in one 16-lane group
      #pragma unroll
      for (int rg = 0; rg < 4; ++rg) {
        float m = -3.0e38f;
        #pragma unroll
        for (int nt = 0; nt < 4; ++nt) m = fmaxf(m, sacc[nt][rg]);
        #pragma unroll
        for (int dd = 1; dd < 16; dd <<= 1) m = fmaxf(m, __shfl_xor(m, dd, 64));
        float s = 0.f, e[4];
        #pragma unroll
        for (int nt = 0; nt < 4; ++nt) { e[nt] = __expf((sacc[nt][rg] - m) * SCALE); s += e[nt]; }
        #pragma unroll
        for (int dd = 1; dd < 16; dd <<= 1) s += __shfl_xor(s, dd, 64);
        float inv = 1.f / s;
        int row = wvid * 16 + rbase + rg;
        #pragma unroll
        for (int nt = 0; nt < 4; ++nt) {
          int col = nt * 16 + l15;
          int off = (row << 7) + (col << 1); off ^= (row & 7) << 4;
          *(unsigned short*)(pb + off) = f2b(e[nt] * inv);
        }
      }
      // V projection -> Vt (separate buffer; no extra barrier needed)
      f32x4 vacc[4][2];
      gemm_g(wqkvo + 2 * 262144, h, vacc);
      #pragma unroll
      for (int nt = 0; nt < 2; ++nt) {
        int d = wvid * 32 + nt * 16 + l15;
        float bi = bv[h * 128 + d];
        #pragma unroll
        for (int mt = 0; mt < 4; ++mt) {
          int j0 = mt * 16 + rbase;            // 4 consecutive tokens
          u16x4 pk;
          #pragma unroll
          for (int rg = 0; rg < 4; ++rg) pk[rg] = f2b(vacc[mt][nt][rg] + bi);
          int off = (d << 7) + (j0 << 1); off ^= (d & 7) << 4;
          *(u16x4*)(vt + off) = pk;
        }
      }
    }
    __syncthreads();
    // ---- Phase 3: attn_h = P @ V (M=64, 32 d-cols/wave, K=64) -> qb ----
    {
      f32x4 pacc[4][2];
      #pragma unroll
      for (int mt = 0; mt < 4; ++mt)
        #pragma unroll
        for (int nt = 0; nt < 2; ++nt) pacc[mt][nt] = (f32x4){0.f, 0.f, 0.f, 0.f};
      #pragma unroll
      for (int kk = 0; kk < 64; kk += 32) {
        int ka = kk + kl;
        bf16x8 afr[4];
        #pragma unroll
        for (int mt = 0; mt < 4; ++mt) {
          int row = mt * 16 + l15;
          int off = (row << 7) + (ka << 1); off ^= (row & 7) << 4;
          afr[mt] = *(const bf16x8*)(pb + off);
        }
        bf16x8 bfr[2];
        #pragma unroll
        for (int nt = 0; nt < 2; ++nt) {
          int d = wvid * 32 + nt * 16 + l15;
          int off = (d << 7) + (ka << 1); off ^= (d & 7) << 4;
          bfr[nt] = *(const bf16x8*)(vt + off);
        }
        #pragma unroll
        for (int mt = 0; mt < 4; ++mt)
          #pragma unroll
          for (int nt = 0; nt < 2; ++nt)
            pacc[mt][nt] = __builtin_amdgcn_mfma_f32_16x16x32_bf16(afr[mt], bfr[nt], pacc[mt][nt], 0, 0, 0);
      }
      #pragma unroll
      for (int nt = 0; nt < 2; ++nt) {
        int d = wvid * 32 + nt * 16 + l15;
        #pragma unroll
        for (int mt = 0; mt < 4; ++mt)
          #pragma unroll
          for (int rg = 0; rg < 4; ++rg) {
            int row = mt * 16 + rbase + rg;
            int off = (row << 8) + (d << 1); off ^= (row & 7) << 4;
            *(unsigned short*)(qb + off) = f2b(pacc[mt][nt][rg]);
          }
      }
    }
    __syncthreads();
    // ---- Phase 4: oacc += attn_h(qb) @ Wo_h^T (128 cols/wave) ----
    {
      #pragma unroll 2
      for (int kk = 0; kk < 128; kk += 32) {
        int ka = kk + kl;
        bf16x8 afr[4];
        #pragma unroll
        for (int mt = 0; mt < 4; ++mt) {
          int row = mt * 16 + l15;
          int off = (row << 8) + (ka << 1); off ^= (row & 7) << 4;
          afr[mt] = *(const bf16x8*)(qb + off);
        }
        bf16x8 bfr[8];
        #pragma unroll
        for (int nt = 0; nt < 8; ++nt) {
          int j = wvid * 128 + nt * 16 + l15;
          bfr[nt] = *(const bf16x8*)(wo + (size_t)j * 512 + h * 128 + ka);
        }
        #pragma unroll
        for (int mt = 0; mt < 4; ++mt)
          #pragma unroll
          for (int nt = 0; nt < 8; ++nt)
            oacc[mt][nt] = __builtin_amdgcn_mfma_f32_16x16x32_bf16(afr[mt], bfr[nt], oacc[mt][nt], 0, 0, 0);
      }
    }
    __syncthreads();
  }

  // ---- epilogue: scatter oacc + bo to valid tokens ----
  #pragma unroll
  for (int mt = 0; mt < 4; ++mt) {
    #pragma unroll
    for (int rg = 0; rg < 4; ++rg) {
      int r = mt * 16 + rbase + rg;
      int gy = wy * 8 + (r >> 3), gx = wx * 8 + (r & 7);
      if (gy < Ht && gx < Wt) {
        float* po = out + ((size_t)b * NTOK + gy * Wt + gx) * C;
        #pragma unroll
        for (int nt = 0; nt < 8; ++nt) {
          int j = wvid * 128 + nt * 16 + l15;
          po[j] = oacc[mt][nt][rg] + bo[j];
        }
      }
    }
  }
}

extern "C" void kernel_launch(void* const* d_in, const int* in_sizes, int n_in,
                              void* d_out, int out_size, void* d_ws, size_t ws_size,
                              hipStream_t stream) {
  const float* x  = (const float*)d_in[0];
  // d_in[1] = t (unused by reference)
  const float* Wq = (const float*)d_in[2];
  const float* bq = (const float*)d_in[3];
  const float* Wk = (const float*)d_in[4];
  const float* bk = (const float*)d_in[5];
  const float* Wv = (const float*)d_in[6];
  const float* bv = (const float*)d_in[7];
  const float* Wo = (const float*)d_in[8];
  const float* bo = (const float*)d_in[9];
  unsigned short* wbf = (unsigned short*)d_ws;   // 4 x 512 x 512 bf16 = 2 MB

  cvt_weights<<<1024, 256, 0, stream>>>(Wq, Wk, Wv, Wo, wbf);

  swmhsa_main<<<BT * NWIN, 256, 0, stream>>>(
      x, wbf, bq, bk, bv, bo, (float*)d_out);
}

// Round 5
// 1381.595 us; speedup vs baseline: 1.8979x; 1.8979x over previous
//
#include <hip/hip_runtime.h>
#include <hip/hip_bf16.h>

using bf16x8 = __attribute__((ext_vector_type(8))) short;
using f32x4  = __attribute__((ext_vector_type(4))) float;
using u16x4  = __attribute__((ext_vector_type(4))) unsigned short;

constexpr int Ht = 60, Wt = 108, C = 512;
constexpr int GWt = 14, NWIN = 112, NTOK = Ht * Wt, BT = 16;
constexpr float SCALE = 0.08838834764831845f;   // 1/sqrt(128)

// kernel-1 LDS (static 40 KB). All tiles XOR-swizzled: byte ^= (row&7)<<4
constexpr int O_Q = 0;       // [64][128] bf16: x-chunk bounce, then Q       16384
constexpr int O_K = 16384;   // [64][128] bf16: K, then Vt [128][64]         16384
constexpr int O_P = 32768;   // [64][64]  bf16: P                             8192

__device__ __forceinline__ unsigned short f2b(float f) {   // f32 -> bf16 RNE
  union { float f; unsigned u; } v; v.f = f;
  unsigned r = v.u + 0x7fffu + ((v.u >> 16) & 1u);
  return (unsigned short)(r >> 16);
}

__global__ void cvt_weights(const float* __restrict__ a, const float* __restrict__ b,
                            const float* __restrict__ c, const float* __restrict__ d,
                            unsigned short* __restrict__ dst) {
  int i = blockIdx.x * blockDim.x + threadIdx.x;   // 262144 threads, 4 f32 each
  int m  = i >> 16;
  int o4 = i & 65535;
  const float* src = (m == 0) ? a : (m == 1) ? b : (m == 2) ? c : d;
  float4 v = *(const float4*)(src + (size_t)o4 * 4);
  u16x4 o;
  o[0] = f2b(v.x); o[1] = f2b(v.y); o[2] = f2b(v.z); o[3] = f2b(v.w);
  *(u16x4*)(dst + (size_t)m * 262144 + (size_t)o4 * 4) = o;
}

// ---------------- kernel 1: QKV + attention, writes attn (f32) into out ----
extern "C" __global__ __launch_bounds__(256, 1)
void swmhsa_attn(const float* __restrict__ x,
                 const unsigned short* __restrict__ wqkvo,   // [4][512][512] bf16
                 const float* __restrict__ bq, const float* __restrict__ bk,
                 const float* __restrict__ bv,
                 float* __restrict__ out)
{
  __shared__ char smem[40960];
  const int tid   = threadIdx.x;
  const int wvid  = tid >> 6;          // wave 0..3
  const int lane  = tid & 63;
  const int l15   = lane & 15;
  const int kl    = (lane >> 4) << 3;  // per-lane k offset in fragments
  const int rbase = (lane >> 4) << 2;  // acc row base

  char* qb = smem + O_Q;
  char* kb = smem + O_K;
  char* pb = smem + O_P;

  const int blk = blockIdx.x;
  const int b   = blk / NWIN;
  const int w   = blk - b * NWIN;
  const int wy  = w / GWt, wx = w - wy * GWt;

  // ---- stage x window into registers: xr[mt][step] = A-frag(rows mt*16+l15,
  //      k = step*32+kl .. +8). 64 VGPR/wave, via 4 LDS bounce chunks ----
  bf16x8 xr[4][16];
  for (int cch = 0; cch < 4; ++cch) {
    // coalesced: 64 rows x 128 k (f32) -> bf16 swizzled into qb
    for (int it = 0; it < 8; ++it) {
      int f  = it * 256 + tid;         // u16x4 index within chunk
      int r  = f >> 5;                 // 32 groups per row
      int c4 = f & 31;
      int gy = wy * 8 + (r >> 3), gx = wx * 8 + (r & 7);
      float4 v = make_float4(0.f, 0.f, 0.f, 0.f);
      if (gy < Ht && gx < Wt)
        v = *(const float4*)(x + ((size_t)b * NTOK + gy * Wt + gx) * C + cch * 128 + c4 * 4);
      u16x4 o;
      o[0] = f2b(v.x); o[1] = f2b(v.y); o[2] = f2b(v.z); o[3] = f2b(v.w);
      int off = (r << 8) + (c4 << 3);
      off ^= (r & 7) << 4;
      *(u16x4*)(qb + off) = o;
    }
    __syncthreads();
    #pragma unroll
    for (int mt = 0; mt < 4; ++mt) {
      int row = mt * 16 + l15;
      #pragma unroll
      for (int s = 0; s < 4; ++s) {
        int off = (row << 8) + ((s * 32 + kl) << 1);
        off ^= (row & 7) << 4;
        xr[mt][cch * 4 + s] = *(const bf16x8*)(qb + off);
      }
    }
    __syncthreads();
  }

  // GEMM: [64 x 32cols-per-wave] = xr @ W_h^T ; A in regs, B bf16 from global
  auto gemm_r = [&](const unsigned short* wm, int h, f32x4 (&acc)[4][2]) {
    #pragma unroll
    for (int mt = 0; mt < 4; ++mt)
      #pragma unroll
      for (int nt = 0; nt < 2; ++nt) acc[mt][nt] = (f32x4){0.f, 0.f, 0.f, 0.f};
    #pragma unroll
    for (int step = 0; step < 16; ++step) {
      int ka = step * 32 + kl;
      bf16x8 bfr[2];
      #pragma unroll
      for (int nt = 0; nt < 2; ++nt) {
        int jg = h * 128 + wvid * 32 + nt * 16 + l15;
        bfr[nt] = *(const bf16x8*)(wm + (size_t)jg * 512 + ka);
      }
      #pragma unroll
      for (int mt = 0; mt < 4; ++mt)
        #pragma unroll
        for (int nt = 0; nt < 2; ++nt)
          acc[mt][nt] = __builtin_amdgcn_mfma_f32_16x16x32_bf16(xr[mt][step], bfr[nt], acc[mt][nt], 0, 0, 0);
    }
  };

  // store acc (row=token, col=feature) row-major [64][128] bf16 + bias, swizzled
  auto store_rm = [&](f32x4 (&acc)[4][2], char* base, const float* bias, int h) {
    #pragma unroll
    for (int nt = 0; nt < 2; ++nt) {
      int col = wvid * 32 + nt * 16 + l15;
      float bi = bias[h * 128 + col];
      #pragma unroll
      for (int mt = 0; mt < 4; ++mt)
        #pragma unroll
        for (int rg = 0; rg < 4; ++rg) {
          int row = mt * 16 + rbase + rg;
          int off = (row << 8) + (col << 1);
          off ^= (row & 7) << 4;
          *(unsigned short*)(base + off) = f2b(acc[mt][nt][rg] + bi);
        }
    }
  };

  for (int h = 0; h < 4; ++h) {
    // ---- Phase 1: Q, K projections -> LDS ----
    {
      f32x4 acc[4][2];
      gemm_r(wqkvo + 0 * 262144, h, acc);      // Q
      store_rm(acc, qb, bq, h);
      gemm_r(wqkvo + 1 * 262144, h, acc);      // K
      store_rm(acc, kb, bk, h);
    }
    __syncthreads();
    // ---- Phase 2: QK^T + softmax -> P ; V projection (regs) ----
    f32x4 vacc[4][2];
    {
      f32x4 sacc[4];
      #pragma unroll
      for (int nt = 0; nt < 4; ++nt) sacc[nt] = (f32x4){0.f, 0.f, 0.f, 0.f};
      #pragma unroll
      for (int kk = 0; kk < 128; kk += 32) {
        int ka = kk + kl;
        int row = wvid * 16 + l15;
        int off = (row << 8) + (ka << 1); off ^= (row & 7) << 4;
        bf16x8 afr = *(const bf16x8*)(qb + off);
        #pragma unroll
        for (int nt = 0; nt < 4; ++nt) {
          int jr = nt * 16 + l15;
          int o2 = (jr << 8) + (ka << 1); o2 ^= (jr & 7) << 4;
          bf16x8 bfr = *(const bf16x8*)(kb + o2);
          sacc[nt] = __builtin_amdgcn_mfma_f32_16x16x32_bf16(afr, bfr, sacc[nt], 0, 0, 0);
        }
      }
      #pragma unroll
      for (int rg = 0; rg < 4; ++rg) {
        float m = -3.0e38f;
        #pragma unroll
        for (int nt = 0; nt < 4; ++nt) m = fmaxf(m, sacc[nt][rg]);
        #pragma unroll
        for (int dd = 1; dd < 16; dd <<= 1) m = fmaxf(m, __shfl_xor(m, dd, 64));
        float s = 0.f, e[4];
        #pragma unroll
        for (int nt = 0; nt < 4; ++nt) { e[nt] = __expf((sacc[nt][rg] - m) * SCALE); s += e[nt]; }
        #pragma unroll
        for (int dd = 1; dd < 16; dd <<= 1) s += __shfl_xor(s, dd, 64);
        float inv = 1.f / s;
        int row = wvid * 16 + rbase + rg;
        #pragma unroll
        for (int nt = 0; nt < 4; ++nt) {
          int col = nt * 16 + l15;
          int off = (row << 7) + (col << 1); off ^= (row & 7) << 4;
          *(unsigned short*)(pb + off) = f2b(e[nt] * inv);
        }
      }
      gemm_r(wqkvo + 2 * 262144, h, vacc);     // V -> registers
    }
    __syncthreads();
    // ---- Phase 3: store V transposed over dead K buffer ----
    {
      #pragma unroll
      for (int nt = 0; nt < 2; ++nt) {
        int d = wvid * 32 + nt * 16 + l15;
        float bi = bv[h * 128 + d];
        #pragma unroll
        for (int mt = 0; mt < 4; ++mt) {
          int j0 = mt * 16 + rbase;
          u16x4 pk;
          #pragma unroll
          for (int rg = 0; rg < 4; ++rg) pk[rg] = f2b(vacc[mt][nt][rg] + bi);
          int off = (d << 7) + (j0 << 1); off ^= (d & 7) << 4;
          *(u16x4*)(kb + off) = pk;
        }
      }
    }
    __syncthreads();
    // ---- Phase 4: attn_h = P @ V -> global f32 (head cols of out) ----
    {
      f32x4 pacc[4][2];
      #pragma unroll
      for (int mt = 0; mt < 4; ++mt)
        #pragma unroll
        for (int nt = 0; nt < 2; ++nt) pacc[mt][nt] = (f32x4){0.f, 0.f, 0.f, 0.f};
      #pragma unroll
      for (int kk = 0; kk < 64; kk += 32) {
        int ka = kk + kl;
        bf16x8 afr[4];
        #pragma unroll
        for (int mt = 0; mt < 4; ++mt) {
          int row = mt * 16 + l15;
          int off = (row << 7) + (ka << 1); off ^= (row & 7) << 4;
          afr[mt] = *(const bf16x8*)(pb + off);
        }
        bf16x8 bfr[2];
        #pragma unroll
        for (int nt = 0; nt < 2; ++nt) {
          int d = wvid * 32 + nt * 16 + l15;
          int off = (d << 7) + (ka << 1); off ^= (d & 7) << 4;
          bfr[nt] = *(const bf16x8*)(kb + off);
        }
        #pragma unroll
        for (int mt = 0; mt < 4; ++mt)
          #pragma unroll
          for (int nt = 0; nt < 2; ++nt)
            pacc[mt][nt] = __builtin_amdgcn_mfma_f32_16x16x32_bf16(afr[mt], bfr[nt], pacc[mt][nt], 0, 0, 0);
      }
      #pragma unroll
      for (int mt = 0; mt < 4; ++mt)
        #pragma unroll
        for (int rg = 0; rg < 4; ++rg) {
          int r = mt * 16 + rbase + rg;
          int gy = wy * 8 + (r >> 3), gx = wx * 8 + (r & 7);
          if (gy < Ht && gx < Wt) {
            float* po = out + ((size_t)b * NTOK + gy * Wt + gx) * C + h * 128;
            #pragma unroll
            for (int nt = 0; nt < 2; ++nt)
              po[wvid * 32 + nt * 16 + l15] = pacc[mt][nt][rg];
          }
        }
    }
    __syncthreads();     // Vt/P still read above; next head rewrites Q/K
  }
}

// ---------------- kernel 2: in-place row-tile GEMM  out = attn @ Wo^T + bo --
extern "C" __global__ __launch_bounds__(256, 1)
void proj_o(const unsigned short* __restrict__ wo,   // [512][512] bf16
            const float* __restrict__ bo,
            float* __restrict__ out)                 // in/out, 103680 x 512
{
  __shared__ char smem[65536];                       // [64][512] bf16, swizzled
  const int tid   = threadIdx.x;
  const int wvid  = tid >> 6;
  const int lane  = tid & 63;
  const int l15   = lane & 15;
  const int kl    = (lane >> 4) << 3;
  const int rbase = (lane >> 4) << 2;
  const size_t row0 = (size_t)blockIdx.x * 64;

  // stage A-tile (f32 -> bf16), coalesced
  for (int it = 0; it < 32; ++it) {
    int f  = it * 256 + tid;           // float4 index, 128 per row
    int r  = f >> 7;
    int c4 = f & 127;
    float4 v = *(const float4*)(out + (row0 + r) * 512 + c4 * 4);
    u16x4 o;
    o[0] = f2b(v.x); o[1] = f2b(v.y); o[2] = f2b(v.z); o[3] = f2b(v.w);
    int off = (r << 10) + (c4 << 3);
    off ^= (r & 7) << 4;
    *(u16x4*)(smem + off) = o;
  }
  __syncthreads();

  for (int half = 0; half < 2; ++half) {
    f32x4 acc[4][4];
    #pragma unroll
    for (int mt = 0; mt < 4; ++mt)
      #pragma unroll
      for (int nt = 0; nt < 4; ++nt) acc[mt][nt] = (f32x4){0.f, 0.f, 0.f, 0.f};
    #pragma unroll 2
    for (int kk = 0; kk < 512; kk += 32) {
      int ka = kk + kl;
      bf16x8 afr[4];
      #pragma unroll
      for (int mt = 0; mt < 4; ++mt) {
        int row = mt * 16 + l15;
        int off = (row << 10) + (ka << 1); off ^= (row & 7) << 4;
        afr[mt] = *(const bf16x8*)(smem + off);
      }
      bf16x8 bfr[4];
      #pragma unroll
      for (int nt = 0; nt < 4; ++nt) {
        int j = wvid * 128 + half * 64 + nt * 16 + l15;
        bfr[nt] = *(const bf16x8*)(wo + (size_t)j * 512 + ka);
      }
      #pragma unroll
      for (int mt = 0; mt < 4; ++mt)
        #pragma unroll
        for (int nt = 0; nt < 4; ++nt)
          acc[mt][nt] = __builtin_amdgcn_mfma_f32_16x16x32_bf16(afr[mt], bfr[nt], acc[mt][nt], 0, 0, 0);
    }
    #pragma unroll
    for (int mt = 0; mt < 4; ++mt)
      #pragma unroll
      for (int rg = 0; rg < 4; ++rg) {
        int r = mt * 16 + rbase + rg;
        float* po = out + (row0 + r) * 512;
        #pragma unroll
        for (int nt = 0; nt < 4; ++nt) {
          int j = wvid * 128 + half * 64 + nt * 16 + l15;
          po[j] = acc[mt][nt][rg] + bo[j];
        }
      }
  }
}

extern "C" void kernel_launch(void* const* d_in, const int* in_sizes, int n_in,
                              void* d_out, int out_size, void* d_ws, size_t ws_size,
                              hipStream_t stream) {
  const float* x  = (const float*)d_in[0];
  // d_in[1] = t (unused by reference)
  const float* Wq = (const float*)d_in[2];
  const float* bq = (const float*)d_in[3];
  const float* Wk = (const float*)d_in[4];
  const float* bk = (const float*)d_in[5];
  const float* Wv = (const float*)d_in[6];
  const float* bv = (const float*)d_in[7];
  const float* Wo = (const float*)d_in[8];
  const float* bo = (const float*)d_in[9];
  unsigned short* wbf = (unsigned short*)d_ws;   // 4 x 512 x 512 bf16 = 2 MB

  cvt_weights<<<1024, 256, 0, stream>>>(Wq, Wk, Wv, Wo, wbf);

  swmhsa_attn<<<BT * NWIN, 256, 0, stream>>>(
      x, wbf, bq, bk, bv, (float*)d_out);

  proj_o<<<(BT * NTOK) / 64, 256, 0, stream>>>(
      wbf + 3 * 262144, bo, (float*)d_out);
}

// Round 7
// 784.479 us; speedup vs baseline: 3.3424x; 1.7612x over previous
//
#include <hip/hip_runtime.h>
#include <hip/hip_bf16.h>

using bf16x8 = __attribute__((ext_vector_type(8))) short;
using f32x4  = __attribute__((ext_vector_type(4))) float;
using u16x4  = __attribute__((ext_vector_type(4))) unsigned short;

constexpr int Ht = 60, Wt = 108, C = 512;
constexpr int GWt = 14, NWIN = 112, NTOK = Ht * Wt, BT = 16;
constexpr int NBLK = BT * NWIN;                   // 1792 window blocks
constexpr float SCALE = 0.08838834764831845f;     // 1/sqrt(128)
constexpr size_t WOFF = 4 * 262144;               // weights: 4x512x512 bf16 elems
constexpr size_t SLABE = (size_t)NBLK * 64 * 512; // attn slab elems (bf16)

__device__ __forceinline__ unsigned short f2b(float f) {   // f32 -> bf16 RNE
  union { float f; unsigned u; } v; v.f = f;
  unsigned r = v.u + 0x7fffu + ((v.u >> 16) & 1u);
  return (unsigned short)(r >> 16);
}

__global__ void cvt_weights(const float* __restrict__ a, const float* __restrict__ b,
                            const float* __restrict__ c, const float* __restrict__ d,
                            unsigned short* __restrict__ dst) {
  int i = blockIdx.x * blockDim.x + threadIdx.x;   // 262144 threads, 4 f32 each
  int m  = i >> 16;
  int o4 = i & 65535;
  const float* src = (m == 0) ? a : (m == 1) ? b : (m == 2) ? c : d;
  float4 v = *(const float4*)(src + (size_t)o4 * 4);
  u16x4 o;
  o[0] = f2b(v.x); o[1] = f2b(v.y); o[2] = f2b(v.z); o[3] = f2b(v.w);
  *(u16x4*)(dst + (size_t)m * 262144 + (size_t)o4 * 4) = o;
}

// ---- K1: per-window QKV + attention -> bf16 attn slab [blk][64][512] in ws --
// LDS 72KB: XL [64][256] 32K @0 | qb 16K @32768 | kb 16K @49152 | pb 8K @65536
// (high x half bounced through qb+kb region into 32 persistent VGPRs)
extern "C" __global__ __launch_bounds__(256, 1)
void qkv_attn(const float* __restrict__ x,
              const unsigned short* __restrict__ wbf,   // [4][512][512] bf16
              const float* __restrict__ bq, const float* __restrict__ bk,
              const float* __restrict__ bv,
              unsigned short* __restrict__ slab)
{
  __shared__ char smem[73728];
  char* qb = smem + 32768;
  char* kb = smem + 49152;
  char* pb = smem + 65536;

  const int tid   = threadIdx.x;
  const int wvid  = tid >> 6;
  const int lane  = tid & 63;
  const int l15   = lane & 15;
  const int kl    = (lane >> 4) << 3;
  const int rbase = (lane >> 4) << 2;

  const int blk = blockIdx.x;
  const int b   = blk / NWIN;
  const int w   = blk - b * NWIN;
  const int wy  = w / GWt, wx = w - wy * GWt;

  // ---- stage x window: low half -> XL (resident), high half -> bounce ----
  for (int it = 0; it < 32; ++it) {
    int f  = it * 256 + tid;           // u16x4 group; 128 per row
    int r  = f >> 7;
    int c4 = f & 127;
    int gy = wy * 8 + (r >> 3), gx = wx * 8 + (r & 7);
    float4 v = make_float4(0.f, 0.f, 0.f, 0.f);
    if (gy < Ht && gx < Wt)
      v = *(const float4*)(x + ((size_t)b * NTOK + gy * Wt + gx) * C + c4 * 4);
    u16x4 o;
    o[0] = f2b(v.x); o[1] = f2b(v.y); o[2] = f2b(v.z); o[3] = f2b(v.w);
    int lc  = c4 & 63;                 // col group within half
    int off = (r << 9) + (lc << 3);
    off ^= (r & 7) << 4;
    off += (c4 >> 6) * 32768;          // half 0 -> @0, half 1 -> bounce @32768
    *(u16x4*)(smem + off) = o;
  }
  __syncthreads();

  // high-half A-fragments -> 32 persistent VGPRs
  bf16x8 xr[4][8];
  #pragma unroll
  for (int mt = 0; mt < 4; ++mt) {
    int row = mt * 16 + l15;
    #pragma unroll
    for (int s = 0; s < 8; ++s) {
      int off = (row << 9) + ((s * 32 + kl) << 1);
      off ^= (row & 7) << 4;
      xr[mt][s] = *(const bf16x8*)(smem + 32768 + off);
    }
  }
  __syncthreads();                     // bounce region becomes qb/kb

  // GEMM: [64 x 32cols/wave] = x_win @ W_h^T ; A: LDS low half + reg high half
  auto gemm_r = [&](const unsigned short* wm, int h, f32x4 (&acc)[4][2]) {
    #pragma unroll
    for (int mt = 0; mt < 4; ++mt)
      #pragma unroll
      for (int nt = 0; nt < 2; ++nt) acc[mt][nt] = (f32x4){0.f, 0.f, 0.f, 0.f};
    #pragma unroll
    for (int s = 0; s < 16; ++s) {
      int ka = s * 32 + kl;            // global k
      bf16x8 afr[4];
      if (s < 8) {
        #pragma unroll
        for (int mt = 0; mt < 4; ++mt) {
          int row = mt * 16 + l15;
          int off = (row << 9) + (ka << 1);
          off ^= (row & 7) << 4;
          afr[mt] = *(const bf16x8*)(smem + off);
        }
      } else {
        #pragma unroll
        for (int mt = 0; mt < 4; ++mt) afr[mt] = xr[mt][s - 8];
      }
      bf16x8 bfr[2];
      #pragma unroll
      for (int nt = 0; nt < 2; ++nt) {
        int jg = h * 128 + wvid * 32 + nt * 16 + l15;
        bfr[nt] = *(const bf16x8*)(wm + (size_t)jg * 512 + ka);
      }
      #pragma unroll
      for (int mt = 0; mt < 4; ++mt)
        #pragma unroll
        for (int nt = 0; nt < 2; ++nt)
          acc[mt][nt] = __builtin_amdgcn_mfma_f32_16x16x32_bf16(afr[mt], bfr[nt], acc[mt][nt], 0, 0, 0);
    }
  };

  auto store_rm = [&](f32x4 (&acc)[4][2], char* base, const float* bias, int h) {
    #pragma unroll
    for (int nt = 0; nt < 2; ++nt) {
      int col = wvid * 32 + nt * 16 + l15;
      float bi = bias[h * 128 + col];
      #pragma unroll
      for (int mt = 0; mt < 4; ++mt)
        #pragma unroll
        for (int rg = 0; rg < 4; ++rg) {
          int row = mt * 16 + rbase + rg;
          int off = (row << 8) + (col << 1);
          off ^= (row & 7) << 4;
          *(unsigned short*)(base + off) = f2b(acc[mt][nt][rg] + bi);
        }
    }
  };

  unsigned short* sl = slab + (size_t)blk * 32768;   // [64][512] bf16

  for (int h = 0; h < 4; ++h) {
    // Phase A: Q, K -> LDS
    {
      f32x4 acc[4][2];
      gemm_r(wbf + 0 * 262144, h, acc);
      store_rm(acc, qb, bq, h);
      gemm_r(wbf + 1 * 262144, h, acc);
      store_rm(acc, kb, bk, h);
    }
    __syncthreads();
    // Phase B: QK^T + softmax -> P ; V gemm -> regs
    f32x4 vacc[4][2];
    {
      f32x4 sacc[4];
      #pragma unroll
      for (int nt = 0; nt < 4; ++nt) sacc[nt] = (f32x4){0.f, 0.f, 0.f, 0.f};
      #pragma unroll
      for (int kk = 0; kk < 128; kk += 32) {
        int ka = kk + kl;
        int row = wvid * 16 + l15;
        int off = (row << 8) + (ka << 1); off ^= (row & 7) << 4;
        bf16x8 afr = *(const bf16x8*)(qb + off);
        #pragma unroll
        for (int nt = 0; nt < 4; ++nt) {
          int jr = nt * 16 + l15;
          int o2 = (jr << 8) + (ka << 1); o2 ^= (jr & 7) << 4;
          bf16x8 bfr = *(const bf16x8*)(kb + o2);
          sacc[nt] = __builtin_amdgcn_mfma_f32_16x16x32_bf16(afr, bfr, sacc[nt], 0, 0, 0);
        }
      }
      #pragma unroll
      for (int rg = 0; rg < 4; ++rg) {
        float m = -3.0e38f;
        #pragma unroll
        for (int nt = 0; nt < 4; ++nt) m = fmaxf(m, sacc[nt][rg]);
        #pragma unroll
        for (int dd = 1; dd < 16; dd <<= 1) m = fmaxf(m, __shfl_xor(m, dd, 64));
        float s = 0.f, e[4];
        #pragma unroll
        for (int nt = 0; nt < 4; ++nt) { e[nt] = __expf((sacc[nt][rg] - m) * SCALE); s += e[nt]; }
        #pragma unroll
        for (int dd = 1; dd < 16; dd <<= 1) s += __shfl_xor(s, dd, 64);
        float inv = 1.f / s;
        int row = wvid * 16 + rbase + rg;
        #pragma unroll
        for (int nt = 0; nt < 4; ++nt) {
          int col = nt * 16 + l15;
          int off = (row << 7) + (col << 1); off ^= (row & 7) << 4;
          *(unsigned short*)(pb + off) = f2b(e[nt] * inv);
        }
      }
      gemm_r(wbf + 2 * 262144, h, vacc);     // V -> registers
    }
    __syncthreads();
    // Phase C: Vt over dead K buffer
    {
      #pragma unroll
      for (int nt = 0; nt < 2; ++nt) {
        int d = wvid * 32 + nt * 16 + l15;
        float bi = bv[h * 128 + d];
        #pragma unroll
        for (int mt = 0; mt < 4; ++mt) {
          int j0 = mt * 16 + rbase;
          u16x4 pk;
          #pragma unroll
          for (int rg = 0; rg < 4; ++rg) pk[rg] = f2b(vacc[mt][nt][rg] + bi);
          int off = (d << 7) + (j0 << 1); off ^= (d & 7) << 4;
          *(u16x4*)(kb + off) = pk;
        }
      }
    }
    __syncthreads();
    // Phase D: attn_h = P @ V -> bf16 slab (head's 128 cols)
    {
      f32x4 pacc[4][2];
      #pragma unroll
      for (int mt = 0; mt < 4; ++mt)
        #pragma unroll
        for (int nt = 0; nt < 2; ++nt) pacc[mt][nt] = (f32x4){0.f, 0.f, 0.f, 0.f};
      #pragma unroll
      for (int kk = 0; kk < 64; kk += 32) {
        int ka = kk + kl;
        bf16x8 afr[4];
        #pragma unroll
        for (int mt = 0; mt < 4; ++mt) {
          int row = mt * 16 + l15;
          int off = (row << 7) + (ka << 1); off ^= (row & 7) << 4;
          afr[mt] = *(const bf16x8*)(pb + off);
        }
        bf16x8 bfr[2];
        #pragma unroll
        for (int nt = 0; nt < 2; ++nt) {
          int d = wvid * 32 + nt * 16 + l15;
          int off = (d << 7) + (ka << 1); off ^= (d & 7) << 4;
          bfr[nt] = *(const bf16x8*)(kb + off);
        }
        #pragma unroll
        for (int mt = 0; mt < 4; ++mt)
          #pragma unroll
          for (int nt = 0; nt < 2; ++nt)
            pacc[mt][nt] = __builtin_amdgcn_mfma_f32_16x16x32_bf16(afr[mt], bfr[nt], pacc[mt][nt], 0, 0, 0);
      }
      #pragma unroll
      for (int nt = 0; nt < 2; ++nt) {
        int d = wvid * 32 + nt * 16 + l15;
        #pragma unroll
        for (int mt = 0; mt < 4; ++mt)
          #pragma unroll
          for (int rg = 0; rg < 4; ++rg) {
            int row = mt * 16 + rbase + rg;
            sl[row * 512 + h * 128 + d] = f2b(pacc[mt][nt][rg]);
          }
      }
    }
    __syncthreads();   // kb/pb reads done before next head rewrites qb/kb
  }
}

// ---- K2: out = slab @ Wo^T + bo  (reads slab, writes out; NOT in-place) ----
extern "C" __global__ __launch_bounds__(256, 1)
void proj_o(const unsigned short* __restrict__ slab,
            const unsigned short* __restrict__ wo,
            const float* __restrict__ bo,
            float* __restrict__ out)
{
  __shared__ char smem[65536];                 // [64][512] bf16, swizzled
  const int tid   = threadIdx.x;
  const int wvid  = tid >> 6;
  const int lane  = tid & 63;
  const int l15   = lane & 15;
  const int kl    = (lane >> 4) << 3;
  const int rbase = (lane >> 4) << 2;

  const int blk = blockIdx.x;
  const int b   = blk / NWIN;
  const int w   = blk - b * NWIN;
  const int wy  = w / GWt, wx = w - wy * GWt;

  const unsigned short* src = slab + (size_t)blk * 32768;
  for (int it = 0; it < 16; ++it) {
    int f  = it * 256 + tid;                   // u16x8 group; 64 per row
    int r  = f >> 6;
    int c8 = f & 63;
    bf16x8 v = *(const bf16x8*)(src + r * 512 + c8 * 8);
    int off = (r << 10) + (c8 << 4);
    off ^= (r & 7) << 4;
    *(bf16x8*)(smem + off) = v;
  }
  __syncthreads();

  for (int half = 0; half < 2; ++half) {
    f32x4 acc[4][4];
    #pragma unroll
    for (int mt = 0; mt < 4; ++mt)
      #pragma unroll
      for (int nt = 0; nt < 4; ++nt) acc[mt][nt] = (f32x4){0.f, 0.f, 0.f, 0.f};
    #pragma unroll 2
    for (int kk = 0; kk < 512; kk += 32) {
      int ka = kk + kl;
      bf16x8 afr[4];
      #pragma unroll
      for (int mt = 0; mt < 4; ++mt) {
        int row = mt * 16 + l15;
        int off = (row << 10) + (ka << 1); off ^= (row & 7) << 4;
        afr[mt] = *(const bf16x8*)(smem + off);
      }
      bf16x8 bfr[4];
      #pragma unroll
      for (int nt = 0; nt < 4; ++nt) {
        int j = wvid * 128 + half * 64 + nt * 16 + l15;
        bfr[nt] = *(const bf16x8*)(wo + (size_t)j * 512 + ka);
      }
      #pragma unroll
      for (int mt = 0; mt < 4; ++mt)
        #pragma unroll
        for (int nt = 0; nt < 4; ++nt)
          acc[mt][nt] = __builtin_amdgcn_mfma_f32_16x16x32_bf16(afr[mt], bfr[nt], acc[mt][nt], 0, 0, 0);
    }
    #pragma unroll
    for (int mt = 0; mt < 4; ++mt)
      #pragma unroll
      for (int rg = 0; rg < 4; ++rg) {
        int r = mt * 16 + rbase + rg;
        int gy = wy * 8 + (r >> 3), gx = wx * 8 + (r & 7);
        if (gy < Ht && gx < Wt) {
          float* po = out + ((size_t)b * NTOK + gy * Wt + gx) * C;
          #pragma unroll
          for (int nt = 0; nt < 4; ++nt) {
            int j = wvid * 128 + half * 64 + nt * 16 + l15;
            po[j] = acc[mt][nt][rg] + bo[j];
          }
        }
      }
  }
}

// ---------------- fallback: proven round-1 monolithic kernel ----------------
constexpr int M_XW = 0, M_AB = 65536, M_KV = 131072, M_P = 147456;
constexpr int M_LDS = 155648;

extern "C" __global__ __launch_bounds__(256, 1)
void swmhsa_mono(const float* __restrict__ x,
                 const unsigned short* __restrict__ wqkvo,
                 const float* __restrict__ bq, const float* __restrict__ bk,
                 const float* __restrict__ bv, const float* __restrict__ bo,
                 float* __restrict__ out)
{
  extern __shared__ char smem[];
  const int tid   = threadIdx.x;
  const int wvid  = tid >> 6;
  const int lane  = tid & 63;
  const int l15   = lane & 15;
  const int kl    = (lane >> 4) << 3;
  const int rbase = (lane >> 4) << 2;

  const int blk = blockIdx.x;
  const int b   = blk / NWIN;
  const int w   = blk - b * NWIN;
  const int wy  = w / GWt, wx = w - wy * GWt;

  for (int it = 0; it < 32; ++it) {
    int f  = it * 256 + tid;
    int r  = f >> 7;
    int c4 = f & 127;
    int gy = wy * 8 + (r >> 3), gx = wx * 8 + (r & 7);
    float4 v = make_float4(0.f, 0.f, 0.f, 0.f);
    if (gy < Ht && gx < Wt)
      v = *(const float4*)(x + ((size_t)b * NTOK + gy * Wt + gx) * C + c4 * 4);
    u16x4 o;
    o[0] = f2b(v.x); o[1] = f2b(v.y); o[2] = f2b(v.z); o[3] = f2b(v.w);
    int off = (r << 10) + (c4 << 3);
    off ^= (r & 7) << 4;
    *(u16x4*)(smem + M_XW + off) = o;
  }
  __syncthreads();

  auto gemm_qkv = [&](const unsigned short* wm, int h, f32x4 (&acc)[4][2]) {
    #pragma unroll
    for (int mt = 0; mt < 4; ++mt)
      #pragma unroll
      for (int nt = 0; nt < 2; ++nt) acc[mt][nt] = (f32x4){0.f, 0.f, 0.f, 0.f};
    for (int kk = 0; kk < 512; kk += 32) {
      int ka = kk + kl;
      bf16x8 afr[4];
      #pragma unroll
      for (int mt = 0; mt < 4; ++mt) {
        int row = mt * 16 + l15;
        int off = (row << 10) + (ka << 1);
        off ^= (row & 7) << 4;
        afr[mt] = *(const bf16x8*)(smem + M_XW + off);
      }
      bf16x8 bfr[2];
      #pragma unroll
      for (int nt = 0; nt < 2; ++nt) {
        int jg = h * 128 + wvid * 32 + nt * 16 + l15;
        bfr[nt] = *(const bf16x8*)(wm + (size_t)jg * 512 + ka);
      }
      #pragma unroll
      for (int mt = 0; mt < 4; ++mt)
        #pragma unroll
        for (int nt = 0; nt < 2; ++nt)
          acc[mt][nt] = __builtin_amdgcn_mfma_f32_16x16x32_bf16(afr[mt], bfr[nt], acc[mt][nt], 0, 0, 0);
    }
  };

  auto store_rm = [&](f32x4 (&acc)[4][2], char* base, const float* bias, int h) {
    #pragma unroll
    for (int nt = 0; nt < 2; ++nt) {
      int col = wvid * 32 + nt * 16 + l15;
      float bi = bias[h * 128 + col];
      #pragma unroll
      for (int mt = 0; mt < 4; ++mt)
        #pragma unroll
        for (int rg = 0; rg < 4; ++rg) {
          int row = mt * 16 + rbase + rg;
          int off = (row << 8) + (col << 1);
          off ^= (row & 7) << 4;
          *(unsigned short*)(base + off) = f2b(acc[mt][nt][rg] + bi);
        }
    }
  };

  for (int h = 0; h < 4; ++h) {
    char* ab = smem + M_AB + h * 16384;
    {
      f32x4 acc[4][2];
      gemm_qkv(wqkvo + 1 * 262144, h, acc);
      store_rm(acc, smem + M_KV, bk, h);
      gemm_qkv(wqkvo + 0 * 262144, h, acc);
      store_rm(acc, ab, bq, h);
    }
    __syncthreads();
    {
      f32x4 sacc[4];
      #pragma unroll
      for (int nt = 0; nt < 4; ++nt) sacc[nt] = (f32x4){0.f, 0.f, 0.f, 0.f};
      #pragma unroll
      for (int kk = 0; kk < 128; kk += 32) {
        int ka = kk + kl;
        int row = wvid * 16 + l15;
        int off = (row << 8) + (ka << 1); off ^= (row & 7) << 4;
        bf16x8 afr = *(const bf16x8*)(ab + off);
        #pragma unroll
        for (int nt = 0; nt < 4; ++nt) {
          int jr = nt * 16 + l15;
          int o2 = (jr << 8) + (ka << 1); o2 ^= (jr & 7) << 4;
          bf16x8 bfr = *(const bf16x8*)(smem + M_KV + o2);
          sacc[nt] = __builtin_amdgcn_mfma_f32_16x16x32_bf16(afr, bfr, sacc[nt], 0, 0, 0);
        }
      }
      #pragma unroll
      for (int rg = 0; rg < 4; ++rg) {
        float m = -3.0e38f;
        #pragma unroll
        for (int nt = 0; nt < 4; ++nt) m = fmaxf(m, sacc[nt][rg]);
        #pragma unroll
        for (int dd = 1; dd < 16; dd <<= 1) m = fmaxf(m, __shfl_xor(m, dd, 64));
        float s = 0.f, e[4];
        #pragma unroll
        for (int nt = 0; nt < 4; ++nt) { e[nt] = __expf((sacc[nt][rg] - m) * SCALE); s += e[nt]; }
        #pragma unroll
        for (int dd = 1; dd < 16; dd <<= 1) s += __shfl_xor(s, dd, 64);
        float inv = 1.f / s;
        int row = wvid * 16 + rbase + rg;
        #pragma unroll
        for (int nt = 0; nt < 4; ++nt) {
          int col = nt * 16 + l15;
          int off = (row << 7) + (col << 1); off ^= (row & 7) << 4;
          *(unsigned short*)(smem + M_P + off) = f2b(e[nt] * inv);
        }
      }
    }
    __syncthreads();
    {
      f32x4 vacc[4][2];
      gemm_qkv(wqkvo + 2 * 262144, h, vacc);
      #pragma unroll
      for (int nt = 0; nt < 2; ++nt) {
        int d = wvid * 32 + nt * 16 + l15;
        float bi = bv[h * 128 + d];
        #pragma unroll
        for (int mt = 0; mt < 4; ++mt) {
          int j0 = mt * 16 + rbase;
          u16x4 pk;
          #pragma unroll
          for (int rg = 0; rg < 4; ++rg) pk[rg] = f2b(vacc[mt][nt][rg] + bi);
          int off = (d << 7) + (j0 << 1); off ^= (d & 7) << 4;
          *(u16x4*)(smem + M_KV + off) = pk;
        }
      }
    }
    __syncthreads();
    {
      f32x4 pacc[4][2];
      #pragma unroll
      for (int mt = 0; mt < 4; ++mt)
        #pragma unroll
        for (int nt = 0; nt < 2; ++nt) pacc[mt][nt] = (f32x4){0.f, 0.f, 0.f, 0.f};
      #pragma unroll
      for (int kk = 0; kk < 64; kk += 32) {
        int ka = kk + kl;
        bf16x8 afr[4];
        #pragma unroll
        for (int mt = 0; mt < 4; ++mt) {
          int row = mt * 16 + l15;
          int off = (row << 7) + (ka << 1); off ^= (row & 7) << 4;
          afr[mt] = *(const bf16x8*)(smem + M_P + off);
        }
        bf16x8 bfr[2];
        #pragma unroll
        for (int nt = 0; nt < 2; ++nt) {
          int d = wvid * 32 + nt * 16 + l15;
          int off = (d << 7) + (ka << 1); off ^= (d & 7) << 4;
          bfr[nt] = *(const bf16x8*)(smem + M_KV + off);
        }
        #pragma unroll
        for (int mt = 0; mt < 4; ++mt)
          #pragma unroll
          for (int nt = 0; nt < 2; ++nt)
            pacc[mt][nt] = __builtin_amdgcn_mfma_f32_16x16x32_bf16(afr[mt], bfr[nt], pacc[mt][nt], 0, 0, 0);
      }
      #pragma unroll
      for (int nt = 0; nt < 2; ++nt) {
        int d = wvid * 32 + nt * 16 + l15;
        #pragma unroll
        for (int mt = 0; mt < 4; ++mt)
          #pragma unroll
          for (int rg = 0; rg < 4; ++rg) {
            int row = mt * 16 + rbase + rg;
            int off = (row << 8) + (d << 1); off ^= (row & 7) << 4;
            *(unsigned short*)(ab + off) = f2b(pacc[mt][nt][rg]);
          }
      }
    }
    __syncthreads();
  }

  const unsigned short* wo = wqkvo + 3 * 262144;
  for (int half = 0; half < 2; ++half) {
    f32x4 oacc[4][4];
    #pragma unroll
    for (int mt = 0; mt < 4; ++mt)
      #pragma unroll
      for (int nt = 0; nt < 4; ++nt) oacc[mt][nt] = (f32x4){0.f, 0.f, 0.f, 0.f};
    for (int kk = 0; kk < 512; kk += 32) {
      const char* abk = smem + M_AB + (kk >> 7) * 16384;
      int ka = (kk & 127) + kl;
      bf16x8 afr[4];
      #pragma unroll
      for (int mt = 0; mt < 4; ++mt) {
        int row = mt * 16 + l15;
        int off = (row << 8) + (ka << 1); off ^= (row & 7) << 4;
        afr[mt] = *(const bf16x8*)(abk + off);
      }
      bf16x8 bfr[4];
      #pragma unroll
      for (int nt = 0; nt < 4; ++nt) {
        int j = wvid * 128 + half * 64 + nt * 16 + l15;
        bfr[nt] = *(const bf16x8*)(wo + (size_t)j * 512 + kk + kl);
      }
      #pragma unroll
      for (int mt = 0; mt < 4; ++mt)
        #pragma unroll
        for (int nt = 0; nt < 4; ++nt)
          oacc[mt][nt] = __builtin_amdgcn_mfma_f32_16x16x32_bf16(afr[mt], bfr[nt], oacc[mt][nt], 0, 0, 0);
    }
    #pragma unroll
    for (int mt = 0; mt < 4; ++mt) {
      #pragma unroll
      for (int rg = 0; rg < 4; ++rg) {
        int r = mt * 16 + rbase + rg;
        int gy = wy * 8 + (r >> 3), gx = wx * 8 + (r & 7);
        if (gy < Ht && gx < Wt) {
          float* po = out + ((size_t)b * NTOK + gy * Wt + gx) * C;
          #pragma unroll
          for (int nt = 0; nt < 4; ++nt) {
            int j = wvid * 128 + half * 64 + nt * 16 + l15;
            po[j] = oacc[mt][nt][rg] + bo[j];
          }
        }
      }
    }
  }
}

extern "C" void kernel_launch(void* const* d_in, const int* in_sizes, int n_in,
                              void* d_out, int out_size, void* d_ws, size_t ws_size,
                              hipStream_t stream) {
  const float* x  = (const float*)d_in[0];
  const float* Wq = (const float*)d_in[2];
  const float* bq = (const float*)d_in[3];
  const float* Wk = (const float*)d_in[4];
  const float* bk = (const float*)d_in[5];
  const float* Wv = (const float*)d_in[6];
  const float* bv = (const float*)d_in[7];
  const float* Wo = (const float*)d_in[8];
  const float* bo = (const float*)d_in[9];
  unsigned short* wbf = (unsigned short*)d_ws;

  cvt_weights<<<1024, 256, 0, stream>>>(Wq, Wk, Wv, Wo, wbf);

  const size_t need = (WOFF + SLABE) * 2;   // 2 MB weights + 117 MB attn slab
  if (ws_size < need) {
    hipFuncSetAttribute((const void*)swmhsa_mono,
                        hipFuncAttributeMaxDynamicSharedMemorySize, M_LDS);
    swmhsa_mono<<<NBLK, 256, M_LDS, stream>>>(x, wbf, bq, bk, bv, bo, (float*)d_out);
    return;
  }

  unsigned short* slab = wbf + WOFF;
  qkv_attn<<<NBLK, 256, 0, stream>>>(x, wbf, bq, bk, bv, slab);
  proj_o<<<NBLK, 256, 0, stream>>>(slab, wbf + 3 * 262144, bo, (float*)d_out);
}